// Round 6
// baseline (273.204 us; speedup 1.0000x reference)
//
#include <hip/hip_runtime.h>

// ======================= shared-scratch tiled GEMM body =======================
// C[m0+m, col0+n] = sum_k A[(m0+m)*lda + k] * B[k*ldb + col0 + n]
// 64 rows x 128 cols per block, 256 threads, 8x4 register tile.
// smem needs 16*68 + 16*132 = 3200 floats.
__device__ __forceinline__ void gemm_body(
    float* __restrict__ smem,
    const float* __restrict__ A, int lda,
    const float* __restrict__ B, int ldb,
    float* __restrict__ C, int ldc, int K,
    int m0, int col0) {
  float* As = smem;            // [16][68]
  float* Bs = smem + 16 * 68;  // [16][132]
  const int t = threadIdx.x;
  const int tn = t & 31, tm = t >> 5;
  const int lam = t >> 2, lak = (t & 3) * 4;
  const int lbk = t >> 4, lbn = (t & 15) * 8;
  float acc[8][4];
#pragma unroll
  for (int i = 0; i < 8; ++i)
#pragma unroll
    for (int j = 0; j < 4; ++j) acc[i][j] = 0.f;
  for (int k0 = 0; k0 < K; k0 += 16) {
    float4 av = *reinterpret_cast<const float4*>(A + (size_t)(m0 + lam) * lda + k0 + lak);
    As[(lak + 0) * 68 + lam] = av.x;
    As[(lak + 1) * 68 + lam] = av.y;
    As[(lak + 2) * 68 + lam] = av.z;
    As[(lak + 3) * 68 + lam] = av.w;
    const float* bp = B + (size_t)(k0 + lbk) * ldb + col0 + lbn;
    float4 b0 = *reinterpret_cast<const float4*>(bp);
    float4 b1 = *reinterpret_cast<const float4*>(bp + 4);
    float* bd = &Bs[lbk * 132 + lbn];
    bd[0] = b0.x; bd[1] = b0.y; bd[2] = b0.z; bd[3] = b0.w;
    bd[4] = b1.x; bd[5] = b1.y; bd[6] = b1.z; bd[7] = b1.w;
    __syncthreads();
#pragma unroll
    for (int kk = 0; kk < 16; ++kk) {
      float4 a0 = *reinterpret_cast<const float4*>(&As[kk * 68 + tm * 8]);
      float4 a1 = *reinterpret_cast<const float4*>(&As[kk * 68 + tm * 8 + 4]);
      float4 bv = *reinterpret_cast<const float4*>(&Bs[kk * 132 + tn * 4]);
      float a[8] = {a0.x, a0.y, a0.z, a0.w, a1.x, a1.y, a1.z, a1.w};
      float b[4] = {bv.x, bv.y, bv.z, bv.w};
#pragma unroll
      for (int i = 0; i < 8; ++i)
#pragma unroll
        for (int j = 0; j < 4; ++j) acc[i][j] = fmaf(a[i], b[j], acc[i][j]);
    }
    __syncthreads();
  }
#pragma unroll
  for (int i = 0; i < 8; ++i) {
    float* cp = C + (size_t)(m0 + tm * 8 + i) * ldc + col0 + tn * 4;
    *reinterpret_cast<float4*>(cp) =
        make_float4(acc[i][0], acc[i][1], acc[i][2], acc[i][3]);
  }
}

// ============== GAT attention body — register-resident x rows =================
// softmax over E neighbors, aggregate in input space. Each lane keeps its
// float4 x-fragments in registers (xr[P]); no full-tile LDS round-trip.
// smem floats: WG*4*FIN + (E+1)*(TPR+4) + (E+1)*4 + E*4.
template <int FIN, int TPR, int E>
__device__ __forceinline__ void gat_body(
    float* __restrict__ smem,
    const float* __restrict__ xself, const float* __restrict__ xneigh,
    const float* __restrict__ waS, const float* __restrict__ waN,
    float* __restrict__ out) {
  constexpr int MR = E + 1;                 // + self row
  constexpr int RPP = 256 / TPR;            // el-groups
  constexpr int P = (MR + RPP - 1) / RPP;   // rows per lane
  constexpr int PSTR = TPR + 4;             // 16B-aligned, bank-rotating
  constexpr int G = TPR / 4;
  constexpr int WG = (TPR == 32) ? RPP / 2 : RPP;  // groups after shfl fold
  float* part2 = smem;                      // [WG][4][FIN]
  float* partial = part2 + WG * 4 * FIN;    // [MR][PSTR]
  float* logitS = partial + MR * PSTR;      // [MR][4]
  float* alpha = logitS + MR * 4;           // [E][4]
  const int t = threadIdx.x;
  const int el = t / TPR;
  const int fl = t % TPR;
  const int f0 = fl * 4;
  float4 wn[4], ws[4];
#pragma unroll
  for (int h = 0; h < 4; ++h) {
    wn[h] = *reinterpret_cast<const float4*>(waN + h * FIN + f0);
    ws[h] = *reinterpret_cast<const float4*>(waS + h * FIN + f0);
  }
  float4 xr[P];
#pragma unroll
  for (int p = 0; p < P; ++p) {
    int e = p * RPP + el;
    if (e < MR) {
      const float* src = (e < E) ? (xneigh + (size_t)e * FIN + f0) : (xself + f0);
      float4 x = *reinterpret_cast<const float4*>(src);
      xr[p] = x;
      float ph[4];
#pragma unroll
      for (int h = 0; h < 4; ++h) {
        float4 w = (e < E) ? wn[h] : ws[h];
        ph[h] = x.x * w.x + x.y * w.y + x.z * w.z + x.w * w.w;
      }
#pragma unroll
      for (int h = 0; h < 4; ++h) {  // quad reduce (DPP)
        ph[h] += __shfl_xor(ph[h], 1);
        ph[h] += __shfl_xor(ph[h], 2);
      }
      if ((t & 3) == 0) {
        int g = fl >> 2;
        *reinterpret_cast<float4*>(partial + e * PSTR + g * 4) =
            make_float4(ph[0], ph[1], ph[2], ph[3]);
      }
    }
  }
  __syncthreads();
  if (t < MR * 4) {
    int e = t >> 2, h = t & 3;
    float v = 0.f;
#pragma unroll
    for (int g = 0; g < G; ++g) v += partial[e * PSTR + g * 4 + h];
    logitS[t] = v;
  }
  __syncthreads();
  if (t < 4) {
    const float es = logitS[E * 4 + t];
    float m = -1e30f;
#pragma unroll
    for (int e = 0; e < E; ++e) {
      float x = es + logitS[e * 4 + t];
      x = (x > 0.f) ? x : 0.2f * x;  // LeakyReLU(0.2)
      m = fmaxf(m, x);
    }
    float s = 0.f;
#pragma unroll
    for (int e = 0; e < E; ++e) {
      float x = es + logitS[e * 4 + t];
      x = (x > 0.f) ? x : 0.2f * x;
      float p = __expf(x - m);
      alpha[e * 4 + t] = p;
      s += p;
    }
    float inv = 1.f / s;
#pragma unroll
    for (int e = 0; e < E; ++e) alpha[e * 4 + t] *= inv;
  }
  __syncthreads();
  // per-lane aggregation from registers
  float4 racc[4];
#pragma unroll
  for (int h = 0; h < 4; ++h) racc[h] = make_float4(0.f, 0.f, 0.f, 0.f);
#pragma unroll
  for (int p = 0; p < P; ++p) {
    int e = p * RPP + el;
    if (e < E) {
      float4 x = xr[p];
#pragma unroll
      for (int h = 0; h < 4; ++h) {
        float a = alpha[e * 4 + h];
        racc[h].x = fmaf(a, x.x, racc[h].x);
        racc[h].y = fmaf(a, x.y, racc[h].y);
        racc[h].z = fmaf(a, x.z, racc[h].z);
        racc[h].w = fmaf(a, x.w, racc[h].w);
      }
    }
  }
  if constexpr (TPR == 32) {
#pragma unroll
    for (int h = 0; h < 4; ++h) {  // fold el pairs within each wave
      racc[h].x += __shfl_xor(racc[h].x, 32);
      racc[h].y += __shfl_xor(racc[h].y, 32);
      racc[h].z += __shfl_xor(racc[h].z, 32);
      racc[h].w += __shfl_xor(racc[h].w, 32);
    }
    if ((t & 32) == 0) {
      int g = t >> 6;
#pragma unroll
      for (int h = 0; h < 4; ++h)
        *reinterpret_cast<float4*>(part2 + (g * 4 + h) * FIN + f0) = racc[h];
    }
  } else {
#pragma unroll
    for (int h = 0; h < 4; ++h)
      *reinterpret_cast<float4*>(part2 + (el * 4 + h) * FIN + f0) = racc[h];
  }
  __syncthreads();
  constexpr int C = FIN / 4;
  for (int o = t; o < FIN; o += 256) {  // FIN = 4 heads * FIN/4 float4-units
    int h = o / C, f = (o % C) * 4;
    float4 acc = make_float4(0.f, 0.f, 0.f, 0.f);
#pragma unroll
    for (int g = 0; g < WG; ++g) {
      float4 v = *reinterpret_cast<const float4*>(part2 + (g * 4 + h) * FIN + f);
      acc.x += v.x; acc.y += v.y; acc.z += v.z; acc.w += v.w;
    }
    *reinterpret_cast<float4*>(out + h * FIN + f) = acc;
  }
}

// ======================= prepA: wa vectors + T = W1_hblk @ Wfc_hblk ===========
__global__ void __launch_bounds__(256) prepA(
    const float* __restrict__ W0, const float* __restrict__ a0s,
    const float* __restrict__ a0n,
    const float* __restrict__ W1, const float* __restrict__ a1s,
    const float* __restrict__ a1n, const float* __restrict__ Wfc,
    float* __restrict__ wa0s, float* __restrict__ wa0n,
    float* __restrict__ wa1s, float* __restrict__ wa1n,
    float* __restrict__ T) {
  __shared__ float smem[3200];
  const int b = blockIdx.x;
  if (b < 64) {
    int h = b >> 4, mb = (b >> 1) & 7, nb = b & 1;
    gemm_body(smem, W1 + h * 128, 512, Wfc + (size_t)h * 32768, 256,
              T + (size_t)h * 131072, 256, 128, mb * 64, nb * 128);
    return;
  }
  int idx = (b - 64) * 256 + threadIdx.x;
  if (idx >= 5120) return;
  const float* W; const float* a; float* dst; int i; int FIN;
  if (idx < 512)       { W = W0; a = a0s; dst = wa0s; i = idx;        FIN = 128; }
  else if (idx < 1024) { W = W0; a = a0n; dst = wa0n; i = idx - 512;  FIN = 128; }
  else if (idx < 3072) { W = W1; a = a1s; dst = wa1s; i = idx - 1024; FIN = 512; }
  else                 { W = W1; a = a1n; dst = wa1n; i = idx - 3072; FIN = 512; }
  int f = i >> 2, h = i & 3;
  const float* wrow = W + (size_t)f * 512 + h * 128;
  const float* arow = a + h * 128;
  float v = 0.f;
#pragma unroll 8
  for (int d = 0; d < 128; ++d) v = fmaf(wrow[d], arow[d], v);
  dst[h * FIN + f] = v;
}

// ======= fusedB: layer-0 attention (11264) + Wfinal gemm (64) + va (16) =======
__global__ void __launch_bounds__(256, 4) fusedB(
    const float* __restrict__ h0, const float* __restrict__ h1,
    const float* __restrict__ h2, const float* __restrict__ wa0s,
    const float* __restrict__ wa0n, float* __restrict__ xagg,
    const float* __restrict__ W0, const float* __restrict__ wa1s,
    const float* __restrict__ wa1n, const float* __restrict__ T,
    float* __restrict__ va1s, float* __restrict__ va1n,
    float* __restrict__ Wfinal) {
  __shared__ float smem[3200];  // max(attn E=25: 3188, gemm: 3200)
  const int b = blockIdx.x;
  if (b < 1024) {
    gat_body<128, 32, 10>(smem, h0 + (size_t)b * 128, h1 + (size_t)b * 1280,
                          wa0s, wa0n, xagg + (size_t)b * 512);
    return;
  }
  if (b < 11264) {
    int g = b - 1024;
    gat_body<128, 32, 25>(smem, h1 + (size_t)g * 128, h2 + (size_t)g * 3200,
                          wa0s, wa0n, xagg + (size_t)b * 512);
    return;
  }
  if (b < 11264 + 64) {
    int g = b - 11264;
    int pair = g >> 2, mb = (g >> 1) & 1, nb = g & 1;
    int h = pair >> 2, h0b = pair & 3;
    gemm_body(smem, W0 + h0b * 128, 512,
              T + (size_t)h * 131072 + (size_t)h0b * 32768, 256,
              Wfinal + (size_t)h * 131072 + (size_t)h0b * 32768, 256, 128,
              mb * 64, nb * 128);
    return;
  }
  int idx = (b - 11328) * 256 + threadIdx.x;
  if (idx >= 4096) return;
  const float* wa = (idx < 2048) ? wa1s : wa1n;
  float* dst = (idx < 2048) ? va1s : va1n;
  int i = idx & 2047;
  int h = i >> 9, h0b = (i >> 7) & 3, f = i & 127;
  const float* w0row = W0 + (size_t)f * 512 + h0b * 128;
  const float* warow = wa + h * 512 + h0b * 128;
  float v = 0.f;
#pragma unroll 8
  for (int n = 0; n < 128; ++n) v = fmaf(w0row[n], warow[n], v);
  dst[i] = v;
}

// ======================= layer 1 on xagg space ================================
__global__ void __launch_bounds__(256, 4) gat_layer1(
    const float* __restrict__ xagg, const float* __restrict__ vaS,
    const float* __restrict__ vaN, float* __restrict__ aggx) {
  __shared__ float smem[5632];  // part2 4096 + partial 1452 + logit 44 + alpha 40
  const int b = blockIdx.x;
  gat_body<512, 128, 10>(smem, xagg + (size_t)b * 512,
                         xagg + (size_t)(1024 + b * 10) * 512, vaS, vaN,
                         aggx + (size_t)b * 2048);
}

// ======================= tail: K-split GEMM + reduce ==========================
__global__ void __launch_bounds__(256) gemm_ksplit(
    const float* __restrict__ A, const float* __restrict__ B,
    float* __restrict__ Cpart) {
  __shared__ float smem[3200];
  const int ks = blockIdx.z;
  gemm_body(smem, A + ks * 256, 2048, B + (size_t)ks * 65536, 256,
            Cpart + (size_t)ks * 262144, 256, 256, blockIdx.x * 64,
            blockIdx.y * 128);
}

__global__ void __launch_bounds__(256) reduce8(
    const float* __restrict__ Cpart, float* __restrict__ out) {
  int i = blockIdx.x * 256 + threadIdx.x;  // float4 index, 65536 total
  const float4* p = reinterpret_cast<const float4*>(Cpart) + i;
  float4 s = p[0];
#pragma unroll
  for (int ks = 1; ks < 8; ++ks) {
    float4 v = p[(size_t)ks * 65536];
    s.x += v.x; s.y += v.y; s.z += v.z; s.w += v.w;
  }
  reinterpret_cast<float4*>(out)[i] = s;
}

extern "C" void kernel_launch(void* const* d_in, const int* in_sizes, int n_in,
                              void* d_out, int out_size, void* d_ws, size_t ws_size,
                              hipStream_t stream) {
  const float* h0  = (const float*)d_in[0];
  const float* h1  = (const float*)d_in[1];
  const float* h2  = (const float*)d_in[2];
  const float* W0  = (const float*)d_in[3];
  const float* a0s = (const float*)d_in[4];
  const float* a0n = (const float*)d_in[5];
  const float* W1  = (const float*)d_in[6];
  const float* a1s = (const float*)d_in[7];
  const float* a1n = (const float*)d_in[8];
  const float* Wfc = (const float*)d_in[9];
  float* out = (float*)d_out;

  float* ws = (float*)d_ws;
  float* wa0s   = ws;                    // [4][128]
  float* wa0n   = wa0s + 512;            // [4][128]
  float* wa1s   = wa0n + 512;            // [4][512]
  float* wa1n   = wa1s + 2048;           // [4][512]
  float* va1s   = wa1n + 2048;           // [4][4][128]
  float* va1n   = va1s + 2048;           // [4][4][128]
  float* T      = va1n + 2048;           // [4][512][256] = 524288
  float* Wfinal = T + 524288;            // [4][512][256] = 524288
  float* xaggA  = Wfinal + 524288;       // [11264][512]  = 5767168
  float* aggx   = xaggA + 11264 * 512;   // [1024][2048]  = 2097152
  float* Cpart  = aggx + 2097152;        // [8][1024][256]= 2097152
  // total ~11.0M floats = 44.1 MB

  prepA<<<84, 256, 0, stream>>>(W0, a0s, a0n, W1, a1s, a1n, Wfc,
                                wa0s, wa0n, wa1s, wa1n, T);
  fusedB<<<11344, 256, 0, stream>>>(h0, h1, h2, wa0s, wa0n, xaggA,
                                    W0, wa1s, wa1n, T, va1s, va1n, Wfinal);
  gat_layer1<<<1024, 256, 0, stream>>>(xaggA, va1s, va1n, aggx);
  gemm_ksplit<<<dim3(16, 2, 8), 256, 0, stream>>>(aggx, Wfinal, Cpart);
  reduce8<<<256, 256, 0, stream>>>(Cpart, out);
}